// Round 16
// baseline (299.307 us; speedup 1.0000x reference)
//
#include <hip/hip_runtime.h>
#include <math.h>

#define BB 32
#define CC 384
#define HH 56
#define WW 56
#define HWSZ (HH*WW)          // 3136
#define EPSF 1e-6f

typedef float float2v __attribute__((ext_vector_type(2)));

// DPP lane-shift within 16-lane rows, zero-fill at row edges (bound_ctrl).
__device__ __forceinline__ float dpp_shr1(float v) {   // lane s gets lane s-1's v; s==0 -> 0
    return __int_as_float(__builtin_amdgcn_update_dpp(
        0, __float_as_int(v), 0x111, 0xF, 0xF, true));
}
__device__ __forceinline__ float dpp_shl1(float v) {   // lane s gets lane s+1's v; s==15 -> 0
    return __int_as_float(__builtin_amdgcn_update_dpp(
        0, __float_as_int(v), 0x101, 0xF, 0xF, true));
}

// ---------------- kernel 1: per-(b,c) mean + max, one wave per plane ----------------
__global__ __launch_bounds__(256) void pool_kernel(const float* __restrict__ x,
                                                   float* __restrict__ xavg,
                                                   float* __restrict__ xmax) {
    int t = threadIdx.x;
    int w = t >> 6, l = t & 63;
    int plane = blockIdx.x * 4 + w;
    const float4* xp = (const float4*)(x + (size_t)plane * HWSZ);
    float s = 0.f, m = -INFINITY;
    for (int i = l; i < HWSZ/4; i += 64) {
        float4 v = xp[i];
        s += v.x + v.y + v.z + v.w;
        m = fmaxf(m, fmaxf(fmaxf(v.x, v.y), fmaxf(v.z, v.w)));
    }
    #pragma unroll
    for (int off = 32; off; off >>= 1) {
        s += __shfl_down(s, off, 64);
        m = fmaxf(m, __shfl_down(m, off, 64));
    }
    if (l == 0) {
        xavg[plane] = s * (1.0f / HWSZ);
        xmax[plane] = m;
    }
}

// ---------------- kernel 2: GEMVs + GELU + Gx (parallel) ----------------
__global__ __launch_bounds__(256) void gemv_kernel(
        const float* __restrict__ xavg, const float* __restrict__ xmax,
        const float* __restrict__ w_avg, const float* __restrict__ b_avg,
        const float* __restrict__ w_max, const float* __restrict__ b_max,
        const float* __restrict__ w_mix,
        float* __restrict__ xw, float* __restrict__ Gx, float* __restrict__ partG) {
    int blk = blockIdx.x;
    int b  = blk / 6;
    int cg = blk - b*6;
    int t  = threadIdx.x;
    int ch = cg*64 + (t >> 2);           // output channel
    int kl = t & 3;                      // k-split lane

    const float4* wa = (const float4*)(w_avg + (size_t)ch * CC) + kl*24;
    const float4* wm = (const float4*)(w_max + (size_t)ch * CC) + kl*24;
    const float4* xa = (const float4*)(xavg + (size_t)b * CC) + kl*24;
    const float4* xm = (const float4*)(xmax + (size_t)b * CC) + kl*24;

    float acc = 0.f;
    #pragma unroll 4
    for (int q = 0; q < 24; ++q) {
        float4 a4 = wa[q], v4 = xa[q];
        acc += a4.x*v4.x + a4.y*v4.y + a4.z*v4.z + a4.w*v4.w;
    }
    #pragma unroll 4
    for (int q = 0; q < 24; ++q) {
        float4 m4 = wm[q], v4 = xm[q];
        acc += m4.x*v4.x + m4.y*v4.y + m4.z*v4.z + m4.w*v4.w;
    }
    acc += __shfl_xor(acc, 1);
    acc += __shfl_xor(acc, 2);

    float val = acc + b_avg[ch] + b_max[ch];
    float xwv = 0.5f * val * (1.0f + erff(val * 0.70710678118654752f));

    float sq = 0.f;
    const float* wr = w_mix + (size_t)ch * 49;
    #pragma unroll
    for (int i = 0; i < 13; ++i) {
        int j = kl + 4*i;
        if (j < 49) { float v = wr[j]; sq += v*v; }
    }
    sq += __shfl_xor(sq, 1);
    sq += __shfl_xor(sq, 2);
    float Gxv = fabsf(xwv) * sqrtf(sq);

    __shared__ float sg[64];
    if (kl == 0) {
        xw[b*CC + ch] = xwv;
        Gx[b*CC + ch] = Gxv;
        sg[t >> 2] = Gxv;
    }
    __syncthreads();
    if (t < 64) {
        float v = sg[t];
        for (int off = 32; off; off >>= 1) v += __shfl_down(v, off, 64);
        if (t == 0) partG[blk] = v;
    }
}

// ---------------- kernel 2b: FGRN tap synthesis -> kern[plane][49] ----------------
__global__ __launch_bounds__(256) void taps_kernel(
        const float* __restrict__ xw, const float* __restrict__ Gx,
        const float* __restrict__ partG, const float* __restrict__ w_mix,
        const float* __restrict__ gamma, const float* __restrict__ beta,
        float* __restrict__ kern) {
    int plane = blockIdx.x * 256 + threadIdx.x;   // 0..12287
    int b = plane / CC;
    int c = plane - b*CC;
    float sG = partG[b*6+0] + partG[b*6+1] + partG[b*6+2]
             + partG[b*6+3] + partG[b*6+4] + partG[b*6+5];
    float xwv = xw[plane];
    float Gxv = Gx[plane];
    float coef = gamma[c] * xwv * (Gxv / (sG * (1.0f/CC) + EPSF));
    float bet  = beta[c];
    const float* wr = w_mix + (size_t)c * 49;
    float* kp = kern + (size_t)plane * 49;
    #pragma unroll
    for (int j = 0; j < 49; ++j) kp[j] = coef * wr[j] + bet;
}

// ---------------- kernel 3: direct-global depthwise 7x7 conv ----------------
// 256 threads = one plane. Lane (s,g): 4-wide x 4-TALL patch (14x14 = 196
// active of 256). Small working set (acc 16 VGPR) + __launch_bounds__(256,6)
// (85-VGPR budget) -> target 6 waves/SIMD (vs 4 at VGPR 124). In-loop loads
// (compiler hoists within budget), taps in SGPRs via readlane, DPP neighbors,
// packed float2 FMA.
__global__ __launch_bounds__(256, 6) void conv_kernel(const float* __restrict__ x,
                                                      const float* __restrict__ kern,
                                                      float* __restrict__ out) {
    int t = threadIdx.x;
    int lane = t & 63;
    int plane = blockIdx.x;
    const float4* xp4 = (const float4*)(x + (size_t)plane * HWSZ);
    float4* op4 = (float4*)(out + (size_t)plane * HWSZ);

    int s = t & 15;                      // col quad 0..15 (14 active)
    int g = t >> 4;                      // row-group 0..15 (14 active)
    bool active = (s < 14) && (g < 14);
    int sc = (s < 14) ? s : 13;
    int gc = (g < 14) ? g : 13;
    int g4 = 4*gc - 3;                   // first input row of this group's window

    // ---- tap load: lane j holds kern[plane][j] (kern padded +64 at end)
    float kv_lane = kern[(size_t)plane * 49 + lane];
    float kfv[49];
    #pragma unroll
    for (int j = 0; j < 49; ++j)
        kfv[j] = __int_as_float(__builtin_amdgcn_readlane(__float_as_int(kv_lane), j));

    float2v acc2[4][2];
    #pragma unroll
    for (int i = 0; i < 4; ++i) {
        acc2[i][0] = (float2v){0.f, 0.f};
        acc2[i][1] = (float2v){0.f, 0.f};
    }

    float4 z4 = make_float4(0.f, 0.f, 0.f, 0.f);

    // out(4gc+oy, 4s+j) += k[ky][kx] * in(4gc+oy+ky-3, 4s+j+kx-3), ky = ry-oy
    #pragma unroll
    for (int ry = 0; ry < 10; ++ry) {
        int ri = g4 + ry;
        int ric = min(max(ri, 0), 55);
        float4 vb = xp4[ric*14 + sc];
        bool ok = ((unsigned)ri < 56u) && active;
        if (!ok) vb = z4;

        float w0 = dpp_shr1(vb.y);       // col 4s-3
        float w1 = dpp_shr1(vb.z);
        float w2 = dpp_shr1(vb.w);
        float w7 = dpp_shl1(vb.x);       // col 4s+4
        float w8 = dpp_shl1(vb.y);
        float w9 = dpp_shl1(vb.z);

        float2v wp[5], wq[4];
        wp[0] = (float2v){w0,   w1};
        wp[1] = (float2v){w2,   vb.x};
        wp[2] = (float2v){vb.y, vb.z};
        wp[3] = (float2v){vb.w, w7};
        wp[4] = (float2v){w8,   w9};
        wq[0] = (float2v){w1,   w2};
        wq[1] = (float2v){vb.x, vb.y};
        wq[2] = (float2v){vb.z, vb.w};
        wq[3] = (float2v){w7,   w8};

        int oy_lo = (ry - 6 > 0) ? (ry - 6) : 0;
        int oy_hi = (ry < 3) ? ry : 3;
        #pragma unroll
        for (int oy = 0; oy < 4; ++oy) {
            if (oy < oy_lo || oy > oy_hi) continue;
            int ky = ry - oy;
            #pragma unroll
            for (int kx = 0; kx < 7; ++kx) {
                float kv = kfv[ky*7 + kx];
                float2v kv2 = {kv, kv};
                float2v pa = (kx & 1) ? wq[kx >> 1]       : wp[kx >> 1];
                float2v pb = (kx & 1) ? wq[(kx >> 1) + 1] : wp[(kx >> 1) + 1];
                acc2[oy][0] = __builtin_elementwise_fma(kv2, pa, acc2[oy][0]);
                acc2[oy][1] = __builtin_elementwise_fma(kv2, pb, acc2[oy][1]);
            }
        }
    }

    if (active) {
        #pragma unroll
        for (int oy = 0; oy < 4; ++oy) {
            int orow = 4*gc + oy;
            float4 o;
            o.x = acc2[oy][0].x; o.y = acc2[oy][0].y;
            o.z = acc2[oy][1].x; o.w = acc2[oy][1].y;
            op4[orow*14 + sc] = o;
        }
    }
}

extern "C" void kernel_launch(void* const* d_in, const int* in_sizes, int n_in,
                              void* d_out, int out_size, void* d_ws, size_t ws_size,
                              hipStream_t stream) {
    const float* x     = (const float*)d_in[0];
    const float* w_avg = (const float*)d_in[1];
    const float* b_avg = (const float*)d_in[2];
    const float* w_max = (const float*)d_in[3];
    const float* b_max = (const float*)d_in[4];
    const float* w_mix = (const float*)d_in[5];
    const float* gamma = (const float*)d_in[6];
    const float* beta  = (const float*)d_in[7];
    float* out = (float*)d_out;

    float* ws    = (float*)d_ws;
    float* xavg  = ws;                      // B*C
    float* xmax  = ws + BB*CC;              // B*C
    float* xwbuf = ws + 2*BB*CC;            // B*C
    float* Gxbuf = ws + 3*BB*CC;            // B*C
    float* partG = ws + 4*BB*CC;            // 192 (+pad to 256)
    float* kern  = ws + 4*BB*CC + 256;      // B*C*49 + 64 pad

    pool_kernel<<<BB*CC/4, 256, 0, stream>>>(x, xavg, xmax);
    gemv_kernel<<<BB*6, 256, 0, stream>>>(xavg, xmax, w_avg, b_avg, w_max, b_max,
                                          w_mix, xwbuf, Gxbuf, partG);
    taps_kernel<<<BB*CC/256, 256, 0, stream>>>(xwbuf, Gxbuf, partG, w_mix, gamma, beta, kern);
    conv_kernel<<<BB*CC, 256, 0, stream>>>(x, kern, out);
}

// Round 17
// 113.662 us; speedup vs baseline: 2.6333x; 2.6333x over previous
//
#include <hip/hip_runtime.h>
#include <math.h>

#define BB 32
#define CC 384
#define HH 56
#define WW 56
#define HWSZ (HH*WW)          // 3136
#define EPSF 1e-6f

typedef float float2v __attribute__((ext_vector_type(2)));

// DPP lane-shift within 16-lane rows, zero-fill at row edges (bound_ctrl).
__device__ __forceinline__ float dpp_shr1(float v) {   // lane s gets lane s-1's v; s==0 -> 0
    return __int_as_float(__builtin_amdgcn_update_dpp(
        0, __float_as_int(v), 0x111, 0xF, 0xF, true));
}
__device__ __forceinline__ float dpp_shl1(float v) {   // lane s gets lane s+1's v; s==15 -> 0
    return __int_as_float(__builtin_amdgcn_update_dpp(
        0, __float_as_int(v), 0x101, 0xF, 0xF, true));
}

// ---------------- kernel 1: per-(b,c) mean + max, one wave per plane ----------------
__global__ __launch_bounds__(256) void pool_kernel(const float* __restrict__ x,
                                                   float* __restrict__ xavg,
                                                   float* __restrict__ xmax) {
    int t = threadIdx.x;
    int w = t >> 6, l = t & 63;
    int plane = blockIdx.x * 4 + w;
    const float4* xp = (const float4*)(x + (size_t)plane * HWSZ);
    float s = 0.f, m = -INFINITY;
    for (int i = l; i < HWSZ/4; i += 64) {
        float4 v = xp[i];
        s += v.x + v.y + v.z + v.w;
        m = fmaxf(m, fmaxf(fmaxf(v.x, v.y), fmaxf(v.z, v.w)));
    }
    #pragma unroll
    for (int off = 32; off; off >>= 1) {
        s += __shfl_down(s, off, 64);
        m = fmaxf(m, __shfl_down(m, off, 64));
    }
    if (l == 0) {
        xavg[plane] = s * (1.0f / HWSZ);
        xmax[plane] = m;
    }
}

// ---------------- kernel 2: GEMVs + GELU + Gx (parallel) ----------------
__global__ __launch_bounds__(256) void gemv_kernel(
        const float* __restrict__ xavg, const float* __restrict__ xmax,
        const float* __restrict__ w_avg, const float* __restrict__ b_avg,
        const float* __restrict__ w_max, const float* __restrict__ b_max,
        const float* __restrict__ w_mix,
        float* __restrict__ xw, float* __restrict__ Gx, float* __restrict__ partG) {
    int blk = blockIdx.x;
    int b  = blk / 6;
    int cg = blk - b*6;
    int t  = threadIdx.x;
    int ch = cg*64 + (t >> 2);           // output channel
    int kl = t & 3;                      // k-split lane

    const float4* wa = (const float4*)(w_avg + (size_t)ch * CC) + kl*24;
    const float4* wm = (const float4*)(w_max + (size_t)ch * CC) + kl*24;
    const float4* xa = (const float4*)(xavg + (size_t)b * CC) + kl*24;
    const float4* xm = (const float4*)(xmax + (size_t)b * CC) + kl*24;

    float acc = 0.f;
    #pragma unroll 4
    for (int q = 0; q < 24; ++q) {
        float4 a4 = wa[q], v4 = xa[q];
        acc += a4.x*v4.x + a4.y*v4.y + a4.z*v4.z + a4.w*v4.w;
    }
    #pragma unroll 4
    for (int q = 0; q < 24; ++q) {
        float4 m4 = wm[q], v4 = xm[q];
        acc += m4.x*v4.x + m4.y*v4.y + m4.z*v4.z + m4.w*v4.w;
    }
    acc += __shfl_xor(acc, 1);
    acc += __shfl_xor(acc, 2);

    float val = acc + b_avg[ch] + b_max[ch];
    float xwv = 0.5f * val * (1.0f + erff(val * 0.70710678118654752f));

    float sq = 0.f;
    const float* wr = w_mix + (size_t)ch * 49;
    #pragma unroll
    for (int i = 0; i < 13; ++i) {
        int j = kl + 4*i;
        if (j < 49) { float v = wr[j]; sq += v*v; }
    }
    sq += __shfl_xor(sq, 1);
    sq += __shfl_xor(sq, 2);
    float Gxv = fabsf(xwv) * sqrtf(sq);

    __shared__ float sg[64];
    if (kl == 0) {
        xw[b*CC + ch] = xwv;
        Gx[b*CC + ch] = Gxv;
        sg[t >> 2] = Gxv;
    }
    __syncthreads();
    if (t < 64) {
        float v = sg[t];
        for (int off = 32; off; off >>= 1) v += __shfl_down(v, off, 64);
        if (t == 0) partG[blk] = v;
    }
}

// ---------------- kernel 2b: FGRN tap synthesis -> kern[plane][49] ----------------
__global__ __launch_bounds__(256) void taps_kernel(
        const float* __restrict__ xw, const float* __restrict__ Gx,
        const float* __restrict__ partG, const float* __restrict__ w_mix,
        const float* __restrict__ gamma, const float* __restrict__ beta,
        float* __restrict__ kern) {
    int plane = blockIdx.x * 256 + threadIdx.x;   // 0..12287
    int b = plane / CC;
    int c = plane - b*CC;
    float sG = partG[b*6+0] + partG[b*6+1] + partG[b*6+2]
             + partG[b*6+3] + partG[b*6+4] + partG[b*6+5];
    float xwv = xw[plane];
    float Gxv = Gx[plane];
    float coef = gamma[c] * xwv * (Gxv / (sG * (1.0f/CC) + EPSF));
    float bet  = beta[c];
    const float* wr = w_mix + (size_t)c * 49;
    float* kp = kern + (size_t)plane * 49;
    #pragma unroll
    for (int j = 0; j < 49; ++j) kp[j] = coef * wr[j] + bet;
}

// ---------------- kernel 3: direct-global depthwise 7x7 conv ----------------
// 128 threads = 2 waves; WAVE w owns plane 2*blockIdx+w ENTIRELY.
// Lane (s,g): 4-wide x 14-TALL patch (s=lane&15 col quad, g=lane>>4 in 0..3).
// 20-row window per lane, rolling 4-deep prefetch (80 row-instances/plane,
// 23% fewer loads than 7-tall), DPP neighbors, packed float2 FMA, taps in
// SGPRs via readlane. 2x work per wave amortizes the load->FMA ramp.
__global__ __launch_bounds__(128) void conv_kernel(const float* __restrict__ x,
                                                   const float* __restrict__ kern,
                                                   float* __restrict__ out) {
    int t = threadIdx.x;
    int lane = t & 63;
    int plane = blockIdx.x * 2 + (t >> 6);
    const float4* xp4 = (const float4*)(x + (size_t)plane * HWSZ);
    float4* op4 = (float4*)(out + (size_t)plane * HWSZ);

    int s = lane & 15;                   // col quad 0..15 (14 active)
    int g = lane >> 4;                   // row-group 0..3
    bool active = (s < 14);
    int sc = active ? s : 13;
    int g14 = 14*g - 3;                  // first input row of this group's window

    // ---- tap load: lane j holds kern[plane][j] (kern padded +64 at end)
    float kv_lane = kern[(size_t)plane * 49 + lane];

    // ---- rolling prefetch, depth 4
    float4 pf[20];
    #pragma unroll
    for (int i = 0; i < 4; ++i) {
        int ri = g14 + i;
        int ric = min(max(ri, 0), 55);
        pf[i] = xp4[ric*14 + sc];
    }

    // ---- taps -> SGPRs
    float kfv[49];
    #pragma unroll
    for (int j = 0; j < 49; ++j)
        kfv[j] = __int_as_float(__builtin_amdgcn_readlane(__float_as_int(kv_lane), j));

    float2v acc2[14][2];
    #pragma unroll
    for (int i = 0; i < 14; ++i) {
        acc2[i][0] = (float2v){0.f, 0.f};
        acc2[i][1] = (float2v){0.f, 0.f};
    }

    float4 z4 = make_float4(0.f, 0.f, 0.f, 0.f);

    // out(14g+oy, 4s+j) += k[ky][kx] * in(14g+oy+ky-3, 4s+j+kx-3), ky = ry-oy
    #pragma unroll
    for (int ry = 0; ry < 20; ++ry) {
        if (ry + 4 < 20) {
            int ri = g14 + ry + 4;
            int ric = min(max(ri, 0), 55);
            pf[ry + 4] = xp4[ric*14 + sc];
        }

        int ri = g14 + ry;
        bool ok = ((unsigned)ri < 56u) && active;
        float4 vb = ok ? pf[ry] : z4;

        float w0 = dpp_shr1(vb.y);       // col 4s-3
        float w1 = dpp_shr1(vb.z);
        float w2 = dpp_shr1(vb.w);
        float w7 = dpp_shl1(vb.x);       // col 4s+4
        float w8 = dpp_shl1(vb.y);
        float w9 = dpp_shl1(vb.z);

        float2v wp[5], wq[4];
        wp[0] = (float2v){w0,   w1};
        wp[1] = (float2v){w2,   vb.x};
        wp[2] = (float2v){vb.y, vb.z};
        wp[3] = (float2v){vb.w, w7};
        wp[4] = (float2v){w8,   w9};
        wq[0] = (float2v){w1,   w2};
        wq[1] = (float2v){vb.x, vb.y};
        wq[2] = (float2v){vb.z, vb.w};
        wq[3] = (float2v){w7,   w8};

        int oy_lo = (ry - 6 > 0) ? (ry - 6) : 0;
        int oy_hi = (ry < 13) ? ry : 13;
        #pragma unroll
        for (int oy = 0; oy < 14; ++oy) {
            if (oy < oy_lo || oy > oy_hi) continue;
            int ky = ry - oy;
            #pragma unroll
            for (int kx = 0; kx < 7; ++kx) {
                float kv = kfv[ky*7 + kx];
                float2v kv2 = {kv, kv};
                float2v pa = (kx & 1) ? wq[kx >> 1]       : wp[kx >> 1];
                float2v pb = (kx & 1) ? wq[(kx >> 1) + 1] : wp[(kx >> 1) + 1];
                acc2[oy][0] = __builtin_elementwise_fma(kv2, pa, acc2[oy][0]);
                acc2[oy][1] = __builtin_elementwise_fma(kv2, pb, acc2[oy][1]);
            }
        }
    }

    if (active) {
        #pragma unroll
        for (int oy = 0; oy < 14; ++oy) {
            int orow = 14*g + oy;
            float4 o;
            o.x = acc2[oy][0].x; o.y = acc2[oy][0].y;
            o.z = acc2[oy][1].x; o.w = acc2[oy][1].y;
            op4[orow*14 + sc] = o;
        }
    }
}

extern "C" void kernel_launch(void* const* d_in, const int* in_sizes, int n_in,
                              void* d_out, int out_size, void* d_ws, size_t ws_size,
                              hipStream_t stream) {
    const float* x     = (const float*)d_in[0];
    const float* w_avg = (const float*)d_in[1];
    const float* b_avg = (const float*)d_in[2];
    const float* w_max = (const float*)d_in[3];
    const float* b_max = (const float*)d_in[4];
    const float* w_mix = (const float*)d_in[5];
    const float* gamma = (const float*)d_in[6];
    const float* beta  = (const float*)d_in[7];
    float* out = (float*)d_out;

    float* ws    = (float*)d_ws;
    float* xavg  = ws;                      // B*C
    float* xmax  = ws + BB*CC;              // B*C
    float* xwbuf = ws + 2*BB*CC;            // B*C
    float* Gxbuf = ws + 3*BB*CC;            // B*C
    float* partG = ws + 4*BB*CC;            // 192 (+pad to 256)
    float* kern  = ws + 4*BB*CC + 256;      // B*C*49 + 64 pad

    pool_kernel<<<BB*CC/4, 256, 0, stream>>>(x, xavg, xmax);
    gemv_kernel<<<BB*6, 256, 0, stream>>>(xavg, xmax, w_avg, b_avg, w_max, b_max,
                                          w_mix, xwbuf, Gxbuf, partG);
    taps_kernel<<<BB*CC/256, 256, 0, stream>>>(xwbuf, Gxbuf, partG, w_mix, gamma, beta, kern);
    conv_kernel<<<BB*CC/2, 128, 0, stream>>>(x, kern, out);
}

// Round 18
// 96.723 us; speedup vs baseline: 3.0945x; 1.1751x over previous
//
#include <hip/hip_runtime.h>
#include <math.h>

#define BB 32
#define CC 384
#define HH 56
#define WW 56
#define HWSZ (HH*WW)          // 3136
#define EPSF 1e-6f

typedef float float2v __attribute__((ext_vector_type(2)));

// DPP lane-shift within 16-lane rows, zero-fill at row edges (bound_ctrl).
__device__ __forceinline__ float dpp_shr1(float v) {   // lane s gets lane s-1's v; s==0 -> 0
    return __int_as_float(__builtin_amdgcn_update_dpp(
        0, __float_as_int(v), 0x111, 0xF, 0xF, true));
}
__device__ __forceinline__ float dpp_shl1(float v) {   // lane s gets lane s+1's v; s==15 -> 0
    return __int_as_float(__builtin_amdgcn_update_dpp(
        0, __float_as_int(v), 0x101, 0xF, 0xF, true));
}

// ---------------- kernel 1: per-(b,c) mean + max, one wave per plane ----------------
__global__ __launch_bounds__(256) void pool_kernel(const float* __restrict__ x,
                                                   float* __restrict__ xavg,
                                                   float* __restrict__ xmax) {
    int t = threadIdx.x;
    int w = t >> 6, l = t & 63;
    int plane = blockIdx.x * 4 + w;
    const float4* xp = (const float4*)(x + (size_t)plane * HWSZ);
    float s = 0.f, m = -INFINITY;
    for (int i = l; i < HWSZ/4; i += 64) {
        float4 v = xp[i];
        s += v.x + v.y + v.z + v.w;
        m = fmaxf(m, fmaxf(fmaxf(v.x, v.y), fmaxf(v.z, v.w)));
    }
    #pragma unroll
    for (int off = 32; off; off >>= 1) {
        s += __shfl_down(s, off, 64);
        m = fmaxf(m, __shfl_down(m, off, 64));
    }
    if (l == 0) {
        xavg[plane] = s * (1.0f / HWSZ);
        xmax[plane] = m;
    }
}

// ---------------- kernel 2: GEMVs + GELU + Gx (parallel) ----------------
__global__ __launch_bounds__(256) void gemv_kernel(
        const float* __restrict__ xavg, const float* __restrict__ xmax,
        const float* __restrict__ w_avg, const float* __restrict__ b_avg,
        const float* __restrict__ w_max, const float* __restrict__ b_max,
        const float* __restrict__ w_mix,
        float* __restrict__ xw, float* __restrict__ Gx, float* __restrict__ partG) {
    int blk = blockIdx.x;
    int b  = blk / 6;
    int cg = blk - b*6;
    int t  = threadIdx.x;
    int ch = cg*64 + (t >> 2);           // output channel
    int kl = t & 3;                      // k-split lane

    const float4* wa = (const float4*)(w_avg + (size_t)ch * CC) + kl*24;
    const float4* wm = (const float4*)(w_max + (size_t)ch * CC) + kl*24;
    const float4* xa = (const float4*)(xavg + (size_t)b * CC) + kl*24;
    const float4* xm = (const float4*)(xmax + (size_t)b * CC) + kl*24;

    float acc = 0.f;
    #pragma unroll 4
    for (int q = 0; q < 24; ++q) {
        float4 a4 = wa[q], v4 = xa[q];
        acc += a4.x*v4.x + a4.y*v4.y + a4.z*v4.z + a4.w*v4.w;
    }
    #pragma unroll 4
    for (int q = 0; q < 24; ++q) {
        float4 m4 = wm[q], v4 = xm[q];
        acc += m4.x*v4.x + m4.y*v4.y + m4.z*v4.z + m4.w*v4.w;
    }
    acc += __shfl_xor(acc, 1);
    acc += __shfl_xor(acc, 2);

    float val = acc + b_avg[ch] + b_max[ch];
    float xwv = 0.5f * val * (1.0f + erff(val * 0.70710678118654752f));

    float sq = 0.f;
    const float* wr = w_mix + (size_t)ch * 49;
    #pragma unroll
    for (int i = 0; i < 13; ++i) {
        int j = kl + 4*i;
        if (j < 49) { float v = wr[j]; sq += v*v; }
    }
    sq += __shfl_xor(sq, 1);
    sq += __shfl_xor(sq, 2);
    float Gxv = fabsf(xwv) * sqrtf(sq);

    __shared__ float sg[64];
    if (kl == 0) {
        xw[b*CC + ch] = xwv;
        Gx[b*CC + ch] = Gxv;
        sg[t >> 2] = Gxv;
    }
    __syncthreads();
    if (t < 64) {
        float v = sg[t];
        for (int off = 32; off; off >>= 1) v += __shfl_down(v, off, 64);
        if (t == 0) partG[blk] = v;
    }
}

// ---------------- kernel 3: tap synthesis + direct-global depthwise 7x7 conv ----------------
// (r10 optimum, restored.) 128 threads = one plane, no LDS. Lane (s,g):
// 4-wide x 7-tall patch. One float4 load per tile row; neighbors via DPP;
// packed float2 FMA (v_pk_fma_f32); taps fused, wave-uniform in SGPRs.
__global__ __launch_bounds__(128) void conv_kernel(const float* __restrict__ x,
                                                   const float* __restrict__ xw,
                                                   const float* __restrict__ Gx,
                                                   const float* __restrict__ partG,
                                                   const float* __restrict__ w_mix,
                                                   const float* __restrict__ gamma,
                                                   const float* __restrict__ beta,
                                                   float* __restrict__ out) {
    int t = threadIdx.x;
    int plane = blockIdx.x;
    const float4* xp4 = (const float4*)(x + (size_t)plane * HWSZ);
    float4* op4 = (float4*)(out + (size_t)plane * HWSZ);

    // ---- tap synthesis: kfv[j] = gamma[c]*xw*Nx * w_mix[c,j] + beta[c]  (wave-uniform SGPRs)
    float kfv[49];
    {
        int b = plane / CC;
        int c = plane - b*CC;
        float sG = partG[b*6+0] + partG[b*6+1] + partG[b*6+2]
                 + partG[b*6+3] + partG[b*6+4] + partG[b*6+5];
        float xwv = xw[plane];
        float Gxv = Gx[plane];
        float gam = gamma[c];
        float bet = beta[c];
        float coef = gam * xwv * (Gxv / (sG * (1.0f/CC) + EPSF));
        const float* wr = w_mix + (size_t)c * 49;
        #pragma unroll
        for (int j = 0; j < 49; ++j) {
            union { float f; int i; } u;
            u.f = coef * wr[j] + bet;
            u.i = __builtin_amdgcn_readfirstlane(u.i);
            kfv[j] = u.f;
        }
    }

    int s = t & 15;                      // col quad (14 active)
    int g = (t >> 4) & 7;                // row-group 0..7
    bool active = (s < 14);
    int sc = active ? s : 13;
    int g7 = 7*g - 3;                    // first input row of this group's window

    float2v acc2[7][2];
    #pragma unroll
    for (int i = 0; i < 7; ++i) {
        acc2[i][0] = (float2v){0.f, 0.f};
        acc2[i][1] = (float2v){0.f, 0.f};
    }

    float4 z4 = make_float4(0.f, 0.f, 0.f, 0.f);

    // out(7g+oy, 4s+j) += k[ky][kx] * in(7g+oy+ky-3, 4s+j+kx-3)
    // w[i] = input col 4s-3+i: w[0..2] left DPP, w[3..6]=vb, w[7..9] right DPP.
    #pragma unroll
    for (int ry = 0; ry < 13; ++ry) {
        int ri = g7 + ry;
        int ric = min(max(ri, 0), 55);
        float4 vb = xp4[ric*14 + sc];
        bool ok = ((unsigned)ri < 56u) && active;
        if (!ok) vb = z4;

        float w0 = dpp_shr1(vb.y);       // col 4s-3
        float w1 = dpp_shr1(vb.z);
        float w2 = dpp_shr1(vb.w);
        float w7 = dpp_shl1(vb.x);       // col 4s+4
        float w8 = dpp_shl1(vb.y);
        float w9 = dpp_shl1(vb.z);

        float2v wp[5], wq[4];
        wp[0] = (float2v){w0,   w1};
        wp[1] = (float2v){w2,   vb.x};
        wp[2] = (float2v){vb.y, vb.z};
        wp[3] = (float2v){vb.w, w7};
        wp[4] = (float2v){w8,   w9};
        wq[0] = (float2v){w1,   w2};
        wq[1] = (float2v){vb.x, vb.y};
        wq[2] = (float2v){vb.z, vb.w};
        wq[3] = (float2v){w7,   w8};

        int oy_lo = (ry - 6 > 0) ? (ry - 6) : 0;
        int oy_hi = (ry < 6) ? ry : 6;
        #pragma unroll
        for (int oy = 0; oy < 7; ++oy) {
            if (oy < oy_lo || oy > oy_hi) continue;
            int ky = ry - oy;
            #pragma unroll
            for (int kx = 0; kx < 7; ++kx) {
                float kv = kfv[ky*7 + kx];
                float2v kv2 = {kv, kv};
                float2v pa = (kx & 1) ? wq[kx >> 1]       : wp[kx >> 1];
                float2v pb = (kx & 1) ? wq[(kx >> 1) + 1] : wp[(kx >> 1) + 1];
                acc2[oy][0] = __builtin_elementwise_fma(kv2, pa, acc2[oy][0]);
                acc2[oy][1] = __builtin_elementwise_fma(kv2, pb, acc2[oy][1]);
            }
        }
    }

    if (active) {
        #pragma unroll
        for (int oy = 0; oy < 7; ++oy) {
            int orow = 7*g + oy;
            float4 o;
            o.x = acc2[oy][0].x; o.y = acc2[oy][0].y;
            o.z = acc2[oy][1].x; o.w = acc2[oy][1].y;
            op4[orow*14 + sc] = o;
        }
    }
}

extern "C" void kernel_launch(void* const* d_in, const int* in_sizes, int n_in,
                              void* d_out, int out_size, void* d_ws, size_t ws_size,
                              hipStream_t stream) {
    const float* x     = (const float*)d_in[0];
    const float* w_avg = (const float*)d_in[1];
    const float* b_avg = (const float*)d_in[2];
    const float* w_max = (const float*)d_in[3];
    const float* b_max = (const float*)d_in[4];
    const float* w_mix = (const float*)d_in[5];
    const float* gamma = (const float*)d_in[6];
    const float* beta  = (const float*)d_in[7];
    float* out = (float*)d_out;

    float* ws    = (float*)d_ws;
    float* xavg  = ws;                      // B*C
    float* xmax  = ws + BB*CC;              // B*C
    float* xwbuf = ws + 2*BB*CC;            // B*C
    float* Gxbuf = ws + 3*BB*CC;            // B*C
    float* partG = ws + 4*BB*CC;            // 192

    pool_kernel<<<BB*CC/4, 256, 0, stream>>>(x, xavg, xmax);
    gemv_kernel<<<BB*6, 256, 0, stream>>>(xavg, xmax, w_avg, b_avg, w_max, b_max,
                                          w_mix, xwbuf, Gxbuf, partG);
    conv_kernel<<<BB*CC, 128, 0, stream>>>(x, xwbuf, Gxbuf, partG, w_mix, gamma, beta, out);
}